// Round 5
// baseline (707.079 us; speedup 1.0000x reference)
//
#include <hip/hip_runtime.h>
#include <cstdint>
#include <cstddef>

#define BB 64
#define TT 512
#define DD 1024
#define UU 128
#define MM (BB*TT)

// mask arrives as jnp bool -> byte layout ambiguous (uint8 vs int32 widening).
// lengths >= 256 so mask element 1 is always true: byte[1]==1 iff uint8 layout.
__device__ __forceinline__ int mask_elem_bytes(const uint8_t* m) {
    return m[1] ? 1 : 4;
}
__device__ __forceinline__ int mask_at(const uint8_t* m, int eb, int idx) {
    return m[(size_t)idx * eb] != 0;   // little-endian: low byte nonzero iff 0/1 value nonzero
}

// ---------------- GEMM: pot = inputs @ kernel + bias + boundary ----------------
#define BM 64
#define KC 32

__global__ __launch_bounds__(256) void gemm_pot(
    const float* __restrict__ A, const float* __restrict__ Bw,
    const float* __restrict__ bias, const float* __restrict__ lb,
    const float* __restrict__ rb, const uint8_t* __restrict__ mask,
    float* __restrict__ out)
{
    __shared__ float As[KC][68];    // [k][m], padded stride 68
    __shared__ float Bs[KC][132];   // [k][u], padded stride 132

    const int tid = threadIdx.x;
    const int m0  = blockIdx.x * BM;
    const int rg  = tid >> 5;      // 0..7  -> rows rg*8 .. rg*8+7
    const int cg  = tid & 31;      // 0..31 -> cols cg*4 .. cg*4+3

    // staging assignments
    const int s_kg  = tid & 7;     // k-group of 4 within chunk
    const int s_row = tid >> 3;    // 0..31 (plus +32 twin)
    const int b_c4  = tid & 31;
    const int b_kr0 = tid >> 5;    // 0..7

    float acc[8][4];
    #pragma unroll
    for (int r = 0; r < 8; ++r)
        #pragma unroll
        for (int e = 0; e < 4; ++e) acc[r][e] = 0.f;

    const float* aptr0 = A + (size_t)(m0 + s_row)      * DD + s_kg * 4;
    const float* aptr1 = A + (size_t)(m0 + s_row + 32) * DD + s_kg * 4;

    float4 a_pre0 = *(const float4*)(aptr0);
    float4 a_pre1 = *(const float4*)(aptr1);
    float4 b_pre[4];
    #pragma unroll
    for (int p = 0; p < 4; ++p)
        b_pre[p] = *(const float4*)(Bw + (size_t)(b_kr0 + p*8) * UU + b_c4*4);

    for (int k0 = 0; k0 < DD; k0 += KC) {
        __syncthreads();   // previous compute done before overwriting LDS
        {
            const float av0[4] = {a_pre0.x, a_pre0.y, a_pre0.z, a_pre0.w};
            const float av1[4] = {a_pre1.x, a_pre1.y, a_pre1.z, a_pre1.w};
            #pragma unroll
            for (int e = 0; e < 4; ++e) {
                As[s_kg*4 + e][s_row]      = av0[e];
                As[s_kg*4 + e][s_row + 32] = av1[e];
            }
            #pragma unroll
            for (int p = 0; p < 4; ++p)
                *(float4*)&Bs[b_kr0 + p*8][b_c4*4] = b_pre[p];
        }
        __syncthreads();

        // prefetch next chunk while computing this one
        if (k0 + KC < DD) {
            a_pre0 = *(const float4*)(aptr0 + k0 + KC);
            a_pre1 = *(const float4*)(aptr1 + k0 + KC);
            #pragma unroll
            for (int p = 0; p < 4; ++p)
                b_pre[p] = *(const float4*)(Bw + (size_t)(k0 + KC + b_kr0 + p*8) * UU + b_c4*4);
        }

        #pragma unroll
        for (int kk = 0; kk < KC; ++kk) {
            float4 b4  = *(const float4*)&Bs[kk][cg*4];
            float4 a40 = *(const float4*)&As[kk][rg*8];
            float4 a41 = *(const float4*)&As[kk][rg*8 + 4];
            const float av[8] = {a40.x, a40.y, a40.z, a40.w, a41.x, a41.y, a41.z, a41.w};
            #pragma unroll
            for (int r = 0; r < 8; ++r) {
                acc[r][0] = fmaf(av[r], b4.x, acc[r][0]);
                acc[r][1] = fmaf(av[r], b4.y, acc[r][1]);
                acc[r][2] = fmaf(av[r], b4.z, acc[r][2]);
                acc[r][3] = fmaf(av[r], b4.w, acc[r][3]);
            }
        }
    }

    const float4 bias4 = *(const float4*)&bias[cg*4];
    const float4 lb4   = *(const float4*)&lb[cg*4];
    const float4 rb4   = *(const float4*)&rb[cg*4];
    const int eb = mask_elem_bytes(mask);

    #pragma unroll
    for (int r = 0; r < 8; ++r) {
        const int m  = m0 + rg*8 + r;
        const int bi = m >> 9;
        const int ti = m & 511;
        const int mt = mask_at(mask, eb, bi*TT + ti);
        const int mp = (ti > 0)      ? mask_at(mask, eb, bi*TT + ti - 1) : 0;
        const int mn = (ti < TT - 1) ? mask_at(mask, eb, bi*TT + ti + 1) : 0;
        const float sflag = (mt && !mp) ? 1.f : 0.f;
        const float eflag = (mt && !mn) ? 1.f : 0.f;
        float4 o;
        o.x = acc[r][0] + bias4.x + sflag*lb4.x + eflag*rb4.x;
        o.y = acc[r][1] + bias4.y + sflag*lb4.y + eflag*rb4.y;
        o.z = acc[r][2] + bias4.z + sflag*lb4.z + eflag*rb4.z;
        o.w = acc[r][3] + bias4.w + sflag*lb4.w + eflag*rb4.w;
        *(float4*)&out[(size_t)m*UU + cg*4] = o;
    }
}

// ---------------- Viterbi forward: state history (+ optional max history) ----------------
template<bool STORE_MX>
__global__ __launch_bounds__(512) void viterbi_fwd(
    const float* __restrict__ pot, const uint8_t* __restrict__ mask,
    const float* __restrict__ chain, float* __restrict__ hist,
    float* __restrict__ mxb)
{
    const int b   = blockIdx.x;
    const int tid = threadIdx.x;
    const int seg = tid >> 7;    // 0..3 -> i in [seg*32, seg*32+32)
    const int j   = tid & 127;

    __shared__ float state_s[128];
    __shared__ float part[4][128];
    __shared__ int   wcnt[8];

    // sequence length via mask popcount (prefix mask)
    const int eb = mask_elem_bytes(mask);
    const int mm = mask_at(mask, eb, b*TT + tid);
    const unsigned long long bal = __ballot(mm);
    if ((tid & 63) == 0) wcnt[tid >> 6] = __popcll(bal);

    // chain column segment into registers: cc[k] = chain[seg*32+k][j]
    float cc[32];
    #pragma unroll
    for (int k = 0; k < 32; ++k) cc[k] = chain[(seg*32 + k)*UU + j];

    float potcur = 0.f, potnx = 0.f;
    if (tid < 128) {
        const float p0 = pot[(size_t)(b*TT)*UU + j];
        state_s[j] = p0;
        hist[(size_t)(b*TT)*UU + j] = p0;
        potcur = pot[(size_t)(b*TT + 1)*UU + j];
    }
    __syncthreads();

    int len = 0;
    #pragma unroll
    for (int w = 0; w < 8; ++w) len += wcnt[w];

    for (int t = 1; t < len; ++t) {
        // max-plus mat-vec segment: fold pairs of sums with v_max3
        float a0 = -3.4e38f, a1 = a0;
        const float4* sp = (const float4*)&state_s[seg*32];
        #pragma unroll
        for (int q = 0; q < 8; ++q) {
            const float4 s4 = sp[q];
            const float t0 = s4.x + cc[4*q + 0];
            const float t1 = s4.y + cc[4*q + 1];
            const float t2 = s4.z + cc[4*q + 2];
            const float t3 = s4.w + cc[4*q + 3];
            a0 = fmaxf(fmaxf(a0, t0), t1);   // -> v_max3_f32
            a1 = fmaxf(fmaxf(a1, t2), t3);   // -> v_max3_f32
        }
        part[seg][j] = fmaxf(a0, a1);
        if (tid < 128 && t + 1 < len)
            potnx = pot[(size_t)(b*TT + t + 1)*UU + j];
        __syncthreads();
        if (tid < 128) {
            const float mx = fmaxf(fmaxf(part[0][j], part[1][j]),
                                   fmaxf(part[2][j], part[3][j]));
            if (STORE_MX)
                mxb[((size_t)b*TT + t)*UU + j] = mx;   // bit-exact max for equality backtrack
            const float ns = potcur + mx;
            state_s[j] = ns;
            hist[((size_t)b*TT + t)*UU + j] = ns;
            potcur = potnx;
        }
        __syncthreads();
    }
}

// ---------------- Backtrack (equality path): no per-step max-reduce ----------------
__global__ __launch_bounds__(64) void viterbi_bt_eq(
    const float* __restrict__ hist, const float* __restrict__ mxb,
    const uint8_t* __restrict__ mask, const float* __restrict__ chain,
    float* __restrict__ oh)
{
    const int b = blockIdx.x;
    const int l = threadIdx.x;

    // chain transposed + rotate swizzle: ct[j][(i+j)&127] = chain[i][j]
    __shared__ float ct[128][128];
    for (int r = 0; r < 256; ++r) {
        const int idx = r*64 + l;
        const int i = idx >> 7;
        const int j = idx & 127;
        ct[j][(i + j) & 127] = chain[i*UU + j];
    }

    // length
    const int eb = mask_elem_bytes(mask);
    int cnt = 0;
    #pragma unroll
    for (int e = 0; e < 8; ++e) cnt += mask_at(mask, eb, b*TT + e*64 + l);
    #pragma unroll
    for (int off = 32; off > 0; off >>= 1) cnt += __shfl_down(cnt, off);
    const int len = __shfl(cnt, 0);
    __syncthreads();

    const float* Hb = hist + (size_t)b*TT*UU;
    const float* Xb = mxb  + (size_t)b*TT*UU;

    // last tag = first-argmax of final state (row len-1) — one-time reduce
    const float v0 = Hb[(size_t)(len-1)*UU + l], v1 = Hb[(size_t)(len-1)*UU + l + 64];
    float mx = fmaxf(v0, v1);
    #pragma unroll
    for (int off = 32; off > 0; off >>= 1) mx = fmaxf(mx, __shfl_xor(mx, off));
    const unsigned long long c0 = __ballot(v0 == mx);
    const unsigned long long c1 = __ballot(v1 == mx);
    int tag = c0 ? __builtin_ctzll(c0) : 64 + __builtin_ctzll(c1);

    // masked tail: tags t = len-1 .. T-1 all equal last_tag (lane-striped, distinct rows)
    for (int t = len + l; t < TT; t += 64)
        oh[((size_t)b*TT + t)*UU + tag] = 1.0f;

    // depth-2 software pipeline of hist/mx rows (addresses independent of tag)
    // at step t: use hist row t-1 (cur) and mx row t (cur)
    const int r2 = (len >= 2) ? len - 2 : 0;
    const int r3 = (len >= 3) ? len - 3 : 0;
    float hc0 = Hb[(size_t)r2*UU + l], hc1 = Hb[(size_t)r2*UU + l + 64];
    float hm0 = Hb[(size_t)r3*UU + l], hm1 = Hb[(size_t)r3*UU + l + 64];
    float xc0 = Xb[(size_t)(len-1)*UU + l], xc1 = Xb[(size_t)(len-1)*UU + l + 64];
    float xm0 = Xb[(size_t)r2*UU + l],      xm1 = Xb[(size_t)r2*UU + l + 64];

    for (int t = len - 1; t >= 1; --t) {
        if (l == 0) oh[((size_t)b*TT + t)*UU + tag] = 1.0f;

        // issue far prefetch (used two iterations ahead)
        const int th = (t >= 3) ? t - 3 : 0;   // hist row for step t-2
        const int tx = (t >= 2) ? t - 2 : 0;   // mx   row for step t-2
        const float hf0 = Hb[(size_t)th*UU + l], hf1 = Hb[(size_t)th*UU + l + 64];
        const float xf0 = Xb[(size_t)tx*UU + l], xf1 = Xb[(size_t)tx*UU + l + 64];

        // target value V = mx[t][tag], broadcast from prefetched regs
        const float Va = __shfl(xc0, tag & 63);
        const float Vb = __shfl(xc1, tag & 63);
        const float V  = (tag < 64) ? Va : Vb;

        // candidates w_i = state[t-1][i] + chain[i][tag] (bit-identical to fwd)
        const float w0 = hc0 + ct[tag][(l + tag) & 127];
        const float w1 = hc1 + ct[tag][(l + 64 + tag) & 127];
        const unsigned long long b0 = __ballot(w0 == V);
        const unsigned long long b1 = __ballot(w1 == V);
        if (b0)      tag = __builtin_ctzll(b0);
        else if (b1) tag = 64 + __builtin_ctzll(b1);
        // (b0|b1 nonzero guaranteed by bit-exactness; guard keeps tag in range)

        // rotate pipeline
        hc0 = hm0; hc1 = hm1; hm0 = hf0; hm1 = hf1;
        xc0 = xm0; xc1 = xm1; xm0 = xf0; xm1 = xf1;
    }
    if (l == 0) oh[((size_t)b*TT)*UU + tag] = 1.0f;
}

// ---------------- Backtrack (fallback): shuffle-max reduce per step ----------------
__global__ __launch_bounds__(64) void viterbi_bt(
    const float* __restrict__ hist, const uint8_t* __restrict__ mask,
    const float* __restrict__ chain, float* __restrict__ oh)
{
    const int b = blockIdx.x;
    const int l = threadIdx.x;

    __shared__ float ct[128][128];
    for (int r = 0; r < 256; ++r) {
        const int idx = r*64 + l;
        const int i = idx >> 7;
        const int j = idx & 127;
        ct[j][(i + j) & 127] = chain[i*UU + j];
    }

    const int eb = mask_elem_bytes(mask);
    int cnt = 0;
    #pragma unroll
    for (int e = 0; e < 8; ++e) cnt += mask_at(mask, eb, b*TT + e*64 + l);
    #pragma unroll
    for (int off = 32; off > 0; off >>= 1) cnt += __shfl_down(cnt, off);
    const int len = __shfl(cnt, 0);
    __syncthreads();

    const float* srow = &hist[((size_t)b*TT + (len - 1))*UU];
    const float v0 = srow[l], v1 = srow[l + 64];
    float mx = fmaxf(v0, v1);
    #pragma unroll
    for (int off = 32; off > 0; off >>= 1) mx = fmaxf(mx, __shfl_xor(mx, off));
    const unsigned long long c0 = __ballot(v0 == mx);
    const unsigned long long c1 = __ballot(v1 == mx);
    int tag = c0 ? __builtin_ctzll(c0) : 64 + __builtin_ctzll(c1);

    for (int t = len + l; t < TT; t += 64)
        oh[((size_t)b*TT + t)*UU + tag] = 1.0f;

    for (int t = len - 1; t >= 1; --t) {
        if (l == 0) oh[((size_t)b*TT + t)*UU + tag] = 1.0f;
        const float* sr = &hist[((size_t)b*TT + (t - 1))*UU];
        const float s0 = sr[l], s1 = sr[l + 64];
        const float w0 = s0 + ct[tag][(l + tag) & 127];
        const float w1 = s1 + ct[tag][(l + 64 + tag) & 127];
        float m2 = fmaxf(w0, w1);
        #pragma unroll
        for (int off = 32; off > 0; off >>= 1) m2 = fmaxf(m2, __shfl_xor(m2, off));
        const unsigned long long b0 = __ballot(w0 == m2);
        const unsigned long long b1 = __ballot(w1 == m2);
        tag = b0 ? __builtin_ctzll(b0) : 64 + __builtin_ctzll(b1);
    }
    if (l == 0) oh[((size_t)b*TT)*UU + tag] = 1.0f;
}

extern "C" void kernel_launch(void* const* d_in, const int* in_sizes, int n_in,
                              void* d_out, int out_size, void* d_ws, size_t ws_size,
                              hipStream_t stream)
{
    (void)in_sizes; (void)n_in; (void)out_size;
    const float*   inp   = (const float*)d_in[0];
    const uint8_t* mask  = (const uint8_t*)d_in[1];
    const float*   kern  = (const float*)d_in[2];
    const float*   bias  = (const float*)d_in[3];
    const float*   chain = (const float*)d_in[4];
    const float*   lb    = (const float*)d_in[5];
    const float*   rb    = (const float*)d_in[6];

    const size_t nel = (size_t)BB*TT*UU;
    float* pot  = (float*)d_out;        // B*T*U potentials
    float* oh   = pot + nel;            // B*T*U one-hot
    float* hist = (float*)d_ws;         // B*T*U state history (16 MB)
    float* mxb  = hist + nel;           // B*T*U max history (16 MB, if room)
    const bool eq_path = ws_size >= 2 * nel * sizeof(float);   // constant across calls

    hipMemsetAsync(oh, 0, nel*sizeof(float), stream);
    gemm_pot<<<MM/BM, 256, 0, stream>>>(inp, kern, bias, lb, rb, mask, pot);
    if (eq_path) {
        viterbi_fwd<true><<<BB, 512, 0, stream>>>(pot, mask, chain, hist, mxb);
        viterbi_bt_eq<<<BB, 64, 0, stream>>>(hist, mxb, mask, chain, oh);
    } else {
        viterbi_fwd<false><<<BB, 512, 0, stream>>>(pot, mask, chain, hist, nullptr);
        viterbi_bt<<<BB, 64, 0, stream>>>(hist, mask, chain, oh);
    }
}

// Round 8
// 704.423 us; speedup vs baseline: 1.0038x; 1.0038x over previous
//
#include <hip/hip_runtime.h>
#include <cstdint>
#include <cstddef>

#define BB 64
#define TT 512
#define DD 1024
#define UU 128
#define MM (BB*TT)

// raw barrier: LDS-ordering only, does NOT drain vmcnt (global stores float free)
#define WAVE_SYNC() do { asm volatile("s_waitcnt lgkmcnt(0)" ::: "memory"); \
                         __builtin_amdgcn_s_barrier(); } while (0)

// mask arrives as jnp bool -> byte layout ambiguous (uint8 vs int32 widening).
// lengths >= 256 so mask element 1 is always true: byte[1]==1 iff uint8 layout.
__device__ __forceinline__ int mask_elem_bytes(const uint8_t* m) {
    return m[1] ? 1 : 4;
}
__device__ __forceinline__ int mask_at(const uint8_t* m, int eb, int idx) {
    return m[(size_t)idx * eb] != 0;
}

// ---------------- GEMM: pot = inputs @ kernel + bias + boundary ----------------
#define BM 64
#define KC 32

__global__ __launch_bounds__(256) void gemm_pot(
    const float* __restrict__ A, const float* __restrict__ Bw,
    const float* __restrict__ bias, const float* __restrict__ lb,
    const float* __restrict__ rb, const uint8_t* __restrict__ mask,
    float* __restrict__ out)
{
    __shared__ float As[KC][68];
    __shared__ float Bs[KC][132];

    const int tid = threadIdx.x;
    const int m0  = blockIdx.x * BM;
    const int rg  = tid >> 5;
    const int cg  = tid & 31;

    const int s_kg  = tid & 7;
    const int s_row = tid >> 3;
    const int b_c4  = tid & 31;
    const int b_kr0 = tid >> 5;

    float acc[8][4];
    #pragma unroll
    for (int r = 0; r < 8; ++r)
        #pragma unroll
        for (int e = 0; e < 4; ++e) acc[r][e] = 0.f;

    const float* aptr0 = A + (size_t)(m0 + s_row)      * DD + s_kg * 4;
    const float* aptr1 = A + (size_t)(m0 + s_row + 32) * DD + s_kg * 4;

    float4 a_pre0 = *(const float4*)(aptr0);
    float4 a_pre1 = *(const float4*)(aptr1);
    float4 b_pre[4];
    #pragma unroll
    for (int p = 0; p < 4; ++p)
        b_pre[p] = *(const float4*)(Bw + (size_t)(b_kr0 + p*8) * UU + b_c4*4);

    for (int k0 = 0; k0 < DD; k0 += KC) {
        __syncthreads();
        {
            const float av0[4] = {a_pre0.x, a_pre0.y, a_pre0.z, a_pre0.w};
            const float av1[4] = {a_pre1.x, a_pre1.y, a_pre1.z, a_pre1.w};
            #pragma unroll
            for (int e = 0; e < 4; ++e) {
                As[s_kg*4 + e][s_row]      = av0[e];
                As[s_kg*4 + e][s_row + 32] = av1[e];
            }
            #pragma unroll
            for (int p = 0; p < 4; ++p)
                *(float4*)&Bs[b_kr0 + p*8][b_c4*4] = b_pre[p];
        }
        __syncthreads();

        if (k0 + KC < DD) {
            a_pre0 = *(const float4*)(aptr0 + k0 + KC);
            a_pre1 = *(const float4*)(aptr1 + k0 + KC);
            #pragma unroll
            for (int p = 0; p < 4; ++p)
                b_pre[p] = *(const float4*)(Bw + (size_t)(k0 + KC + b_kr0 + p*8) * UU + b_c4*4);
        }

        #pragma unroll
        for (int kk = 0; kk < KC; ++kk) {
            float4 b4  = *(const float4*)&Bs[kk][cg*4];
            float4 a40 = *(const float4*)&As[kk][rg*8];
            float4 a41 = *(const float4*)&As[kk][rg*8 + 4];
            const float av[8] = {a40.x, a40.y, a40.z, a40.w, a41.x, a41.y, a41.z, a41.w};
            #pragma unroll
            for (int r = 0; r < 8; ++r) {
                acc[r][0] = fmaf(av[r], b4.x, acc[r][0]);
                acc[r][1] = fmaf(av[r], b4.y, acc[r][1]);
                acc[r][2] = fmaf(av[r], b4.z, acc[r][2]);
                acc[r][3] = fmaf(av[r], b4.w, acc[r][3]);
            }
        }
    }

    const float4 bias4 = *(const float4*)&bias[cg*4];
    const float4 lb4   = *(const float4*)&lb[cg*4];
    const float4 rb4   = *(const float4*)&rb[cg*4];
    const int eb = mask_elem_bytes(mask);

    #pragma unroll
    for (int r = 0; r < 8; ++r) {
        const int m  = m0 + rg*8 + r;
        const int bi = m >> 9;
        const int ti = m & 511;
        const int mt = mask_at(mask, eb, bi*TT + ti);
        const int mp = (ti > 0)      ? mask_at(mask, eb, bi*TT + ti - 1) : 0;
        const int mn = (ti < TT - 1) ? mask_at(mask, eb, bi*TT + ti + 1) : 0;
        const float sflag = (mt && !mp) ? 1.f : 0.f;
        const float eflag = (mt && !mn) ? 1.f : 0.f;
        float4 o;
        o.x = acc[r][0] + bias4.x + sflag*lb4.x + eflag*rb4.x;
        o.y = acc[r][1] + bias4.y + sflag*lb4.y + eflag*rb4.y;
        o.z = acc[r][2] + bias4.z + sflag*lb4.z + eflag*rb4.z;
        o.w = acc[r][3] + bias4.w + sflag*lb4.w + eflag*rb4.w;
        *(float4*)&out[(size_t)m*UU + cg*4] = o;
    }
}

// ---------------- Viterbi forward: 1 raw barrier/step, no vmcnt drain ----------------
// 512 thr = 8 waves. Wave w keeps a PRIVATE dbuf state st[w][2][128]; only the
// partial-max buffer part[2][4][132] crosses waves (guarded by the one barrier).
// Phase3 (reduce+update) is done redundantly by every wave -> no cross-wave state dep.
// Global hist/mxb stores are wave0-only, fire-and-forget, never drained.
template<bool STORE_MX>
__global__ __launch_bounds__(512) void viterbi_fwd(
    const float* __restrict__ pot, const uint8_t* __restrict__ mask,
    const float* __restrict__ chain, float* __restrict__ hist,
    float* __restrict__ mxb)
{
    const int b   = blockIdx.x;
    const int tid = threadIdx.x;
    const int w   = tid >> 6;    // wave 0..7
    const int l   = tid & 63;    // lane
    const int seg = tid >> 7;    // 0..3 -> i in [seg*32, seg*32+32)
    const int j   = tid & 127;   // column for phase1

    __shared__ float st[8][2][128];     // per-wave private state, dbuf
    __shared__ float part[2][4][132];   // [parity][seg][j], padded
    __shared__ int   wcnt[8];

    const int eb = mask_elem_bytes(mask);
    const int mm = mask_at(mask, eb, b*TT + tid);
    const unsigned long long bal = __ballot(mm);
    if (l == 0) wcnt[w] = __popcll(bal);

    // chain column segment: cc[k] = chain[seg*32+k][j]
    float cc[32];
    #pragma unroll
    for (int k = 0; k < 32; ++k) cc[k] = chain[(seg*32 + k)*UU + j];

    const float* Pb = pot + (size_t)b*TT*UU;
    float* Hb = hist + (size_t)b*TT*UU;
    float* Xb = STORE_MX ? (mxb + (size_t)b*TT*UU) : nullptr;

    // init state t=0 (every wave its own copy); wave0 writes hist row 0
    {
        const float p0 = Pb[l], p1 = Pb[l + 64];
        st[w][0][l] = p0; st[w][0][l + 64] = p1;
        if (w == 0) { Hb[l] = p0; Hb[l + 64] = p1; }
    }
    float potc0 = Pb[(size_t)UU + l], potc1 = Pb[(size_t)UU + l + 64]; // row 1 (len>=2 always)
    __syncthreads();

    int len = 0;
    #pragma unroll
    for (int q = 0; q < 8; ++q) len += wcnt[q];

    for (int t = 1; t < len; ++t) {
        const int cur = (t - 1) & 1;

        // ---- phase1: partial max over own i-segment for column j ----
        float a0 = -3.4e38f, a1 = a0;
        const float4* sp = (const float4*)&st[w][cur][seg*32];   // wave-uniform (broadcast)
        #pragma unroll
        for (int q = 0; q < 8; ++q) {
            const float4 s4 = sp[q];
            const float t0 = s4.x + cc[4*q + 0];
            const float t1 = s4.y + cc[4*q + 1];
            const float t2 = s4.z + cc[4*q + 2];
            const float t3 = s4.w + cc[4*q + 3];
            a0 = fmaxf(fmaxf(a0, t0), t1);   // v_max3_f32
            a1 = fmaxf(fmaxf(a1, t2), t3);   // v_max3_f32
        }
        part[cur][seg][j] = fmaxf(a0, a1);

        // prefetch next pot row (consumed next step; waited by compiler at use)
        float pn0 = 0.f, pn1 = 0.f;
        if (t + 1 < len) {
            pn0 = Pb[(size_t)(t + 1)*UU + l];
            pn1 = Pb[(size_t)(t + 1)*UU + l + 64];
        }

        WAVE_SYNC();   // lgkmcnt(0) + raw s_barrier: part[] visible, stores NOT drained

        // ---- phase3: every wave reduces all 128 columns (2 per lane) ----
        const float m0 = fmaxf(fmaxf(fmaxf(part[cur][0][l],      part[cur][1][l]),
                                     part[cur][2][l]),      part[cur][3][l]);
        const float m1 = fmaxf(fmaxf(fmaxf(part[cur][0][l + 64], part[cur][1][l + 64]),
                                     part[cur][2][l + 64]), part[cur][3][l + 64]);
        const float ns0 = potc0 + m0;
        const float ns1 = potc1 + m1;
        st[w][cur ^ 1][l]      = ns0;
        st[w][cur ^ 1][l + 64] = ns1;
        if (w == 0) {
            Hb[(size_t)t*UU + l]      = ns0;
            Hb[(size_t)t*UU + l + 64] = ns1;
            if (STORE_MX) {
                Xb[(size_t)t*UU + l]      = m0;
                Xb[(size_t)t*UU + l + 64] = m1;
            }
        }
        potc0 = pn0; potc1 = pn1;
    }
}

// ---------------- Backtrack (equality path): no per-step max-reduce ----------------
__global__ __launch_bounds__(64) void viterbi_bt_eq(
    const float* __restrict__ hist, const float* __restrict__ mxb,
    const uint8_t* __restrict__ mask, const float* __restrict__ chain,
    float* __restrict__ oh)
{
    const int b = blockIdx.x;
    const int l = threadIdx.x;

    __shared__ float ct[128][128];
    for (int r = 0; r < 256; ++r) {
        const int idx = r*64 + l;
        const int i = idx >> 7;
        const int j = idx & 127;
        ct[j][(i + j) & 127] = chain[i*UU + j];
    }

    const int eb = mask_elem_bytes(mask);
    int cnt = 0;
    #pragma unroll
    for (int e = 0; e < 8; ++e) cnt += mask_at(mask, eb, b*TT + e*64 + l);
    #pragma unroll
    for (int off = 32; off > 0; off >>= 1) cnt += __shfl_down(cnt, off);
    const int len = __shfl(cnt, 0);
    __syncthreads();

    const float* Hb = hist + (size_t)b*TT*UU;
    const float* Xb = mxb  + (size_t)b*TT*UU;

    const float v0 = Hb[(size_t)(len-1)*UU + l], v1 = Hb[(size_t)(len-1)*UU + l + 64];
    float mx = fmaxf(v0, v1);
    #pragma unroll
    for (int off = 32; off > 0; off >>= 1) mx = fmaxf(mx, __shfl_xor(mx, off));
    const unsigned long long c0 = __ballot(v0 == mx);
    const unsigned long long c1 = __ballot(v1 == mx);
    int tag = c0 ? __builtin_ctzll(c0) : 64 + __builtin_ctzll(c1);

    for (int t = len + l; t < TT; t += 64)
        oh[((size_t)b*TT + t)*UU + tag] = 1.0f;

    const int r2 = (len >= 2) ? len - 2 : 0;
    const int r3 = (len >= 3) ? len - 3 : 0;
    float hc0 = Hb[(size_t)r2*UU + l], hc1 = Hb[(size_t)r2*UU + l + 64];
    float hm0 = Hb[(size_t)r3*UU + l], hm1 = Hb[(size_t)r3*UU + l + 64];
    float xc0 = Xb[(size_t)(len-1)*UU + l], xc1 = Xb[(size_t)(len-1)*UU + l + 64];
    float xm0 = Xb[(size_t)r2*UU + l],      xm1 = Xb[(size_t)r2*UU + l + 64];

    for (int t = len - 1; t >= 1; --t) {
        if (l == 0) oh[((size_t)b*TT + t)*UU + tag] = 1.0f;

        const int th = (t >= 3) ? t - 3 : 0;
        const int tx = (t >= 2) ? t - 2 : 0;
        const float hf0 = Hb[(size_t)th*UU + l], hf1 = Hb[(size_t)th*UU + l + 64];
        const float xf0 = Xb[(size_t)tx*UU + l], xf1 = Xb[(size_t)tx*UU + l + 64];

        const float Va = __shfl(xc0, tag & 63);
        const float Vb = __shfl(xc1, tag & 63);
        const float V  = (tag < 64) ? Va : Vb;

        const float w0 = hc0 + ct[tag][(l + tag) & 127];
        const float w1 = hc1 + ct[tag][(l + 64 + tag) & 127];
        const unsigned long long b0 = __ballot(w0 == V);
        const unsigned long long b1 = __ballot(w1 == V);
        if (b0)      tag = __builtin_ctzll(b0);
        else if (b1) tag = 64 + __builtin_ctzll(b1);

        hc0 = hm0; hc1 = hm1; hm0 = hf0; hm1 = hf1;
        xc0 = xm0; xc1 = xm1; xm0 = xf0; xm1 = xf1;
    }
    if (l == 0) oh[((size_t)b*TT)*UU + tag] = 1.0f;
}

// ---------------- Backtrack (fallback): shuffle-max reduce per step ----------------
__global__ __launch_bounds__(64) void viterbi_bt(
    const float* __restrict__ hist, const uint8_t* __restrict__ mask,
    const float* __restrict__ chain, float* __restrict__ oh)
{
    const int b = blockIdx.x;
    const int l = threadIdx.x;

    __shared__ float ct[128][128];
    for (int r = 0; r < 256; ++r) {
        const int idx = r*64 + l;
        const int i = idx >> 7;
        const int j = idx & 127;
        ct[j][(i + j) & 127] = chain[i*UU + j];
    }

    const int eb = mask_elem_bytes(mask);
    int cnt = 0;
    #pragma unroll
    for (int e = 0; e < 8; ++e) cnt += mask_at(mask, eb, b*TT + e*64 + l);
    #pragma unroll
    for (int off = 32; off > 0; off >>= 1) cnt += __shfl_down(cnt, off);
    const int len = __shfl(cnt, 0);
    __syncthreads();

    const float* srow = &hist[((size_t)b*TT + (len - 1))*UU];
    const float v0 = srow[l], v1 = srow[l + 64];
    float mx = fmaxf(v0, v1);
    #pragma unroll
    for (int off = 32; off > 0; off >>= 1) mx = fmaxf(mx, __shfl_xor(mx, off));
    const unsigned long long c0 = __ballot(v0 == mx);
    const unsigned long long c1 = __ballot(v1 == mx);
    int tag = c0 ? __builtin_ctzll(c0) : 64 + __builtin_ctzll(c1);

    for (int t = len + l; t < TT; t += 64)
        oh[((size_t)b*TT + t)*UU + tag] = 1.0f;

    for (int t = len - 1; t >= 1; --t) {
        if (l == 0) oh[((size_t)b*TT + t)*UU + tag] = 1.0f;
        const float* sr = &hist[((size_t)b*TT + (t - 1))*UU];
        const float s0 = sr[l], s1 = sr[l + 64];
        const float w0 = s0 + ct[tag][(l + tag) & 127];
        const float w1 = s1 + ct[tag][(l + 64 + tag) & 127];
        float m2 = fmaxf(w0, w1);
        #pragma unroll
        for (int off = 32; off > 0; off >>= 1) m2 = fmaxf(m2, __shfl_xor(m2, off));
        const unsigned long long b0 = __ballot(w0 == m2);
        const unsigned long long b1 = __ballot(w1 == m2);
        tag = b0 ? __builtin_ctzll(b0) : 64 + __builtin_ctzll(b1);
    }
    if (l == 0) oh[((size_t)b*TT)*UU + tag] = 1.0f;
}

extern "C" void kernel_launch(void* const* d_in, const int* in_sizes, int n_in,
                              void* d_out, int out_size, void* d_ws, size_t ws_size,
                              hipStream_t stream)
{
    (void)in_sizes; (void)n_in; (void)out_size;
    const float*   inp   = (const float*)d_in[0];
    const uint8_t* mask  = (const uint8_t*)d_in[1];
    const float*   kern  = (const float*)d_in[2];
    const float*   bias  = (const float*)d_in[3];
    const float*   chain = (const float*)d_in[4];
    const float*   lb    = (const float*)d_in[5];
    const float*   rb    = (const float*)d_in[6];

    const size_t nel = (size_t)BB*TT*UU;
    float* pot  = (float*)d_out;
    float* oh   = pot + nel;
    float* hist = (float*)d_ws;
    float* mxb  = hist + nel;
    const bool eq_path = ws_size >= 2 * nel * sizeof(float);

    hipMemsetAsync(oh, 0, nel*sizeof(float), stream);
    gemm_pot<<<MM/BM, 256, 0, stream>>>(inp, kern, bias, lb, rb, mask, pot);
    if (eq_path) {
        viterbi_fwd<true><<<BB, 512, 0, stream>>>(pot, mask, chain, hist, mxb);
        viterbi_bt_eq<<<BB, 64, 0, stream>>>(hist, mxb, mask, chain, oh);
    } else {
        viterbi_fwd<false><<<BB, 512, 0, stream>>>(pot, mask, chain, hist, nullptr);
        viterbi_bt<<<BB, 64, 0, stream>>>(hist, mask, chain, oh);
    }
}